// Round 16
// baseline (231.810 us; speedup 1.0000x reference)
//
#include <hip/hip_runtime.h>
#include <hip/hip_bf16.h>
#include <math.h>

#define EMBED 1024
#define NHEADS 16
#define HDIM 64
#define BATCH 4
#define SQL 1024
#define SKL 2048
#define PSC 0.18033688f   // 0.125 * log2(e)  (folded into Q projection)

typedef unsigned short u16;
typedef __attribute__((ext_vector_type(4))) float f32x4;
typedef __attribute__((ext_vector_type(8))) __bf16 bf16x8;
typedef __attribute__((ext_vector_type(8))) short s16x8;
typedef __attribute__((ext_vector_type(4))) short s16x4;
typedef __attribute__((ext_vector_type(8))) u16 u16x8;

__device__ __forceinline__ u16 f2bf(float x) {
    __hip_bfloat16 h = __float2bfloat16(x);
    return *reinterpret_cast<u16*>(&h);
}
__device__ __forceinline__ float bf2f(u16 u) {
    __hip_bfloat16 h;
    *reinterpret_cast<u16*>(&h) = u;
    return __bfloat162float(h);
}
__device__ __forceinline__ f32x4 mfma16(s16x8 a, s16x8 b, f32x4 c) {
    return __builtin_amdgcn_mfma_f32_16x16x32_bf16(
        __builtin_bit_cast(bf16x8, a), __builtin_bit_cast(bf16x8, b), c, 0, 0, 0);
}
__device__ __forceinline__ f32x4 mfma16k16(s16x4 a, s16x4 b, f32x4 c) {
    return __builtin_amdgcn_mfma_f32_16x16x16bf16_1k(a, b, c, 0, 0, 0);
}
__device__ __forceinline__ void gload16(const void* g, void* l) {
    __builtin_amdgcn_global_load_lds(
        (const __attribute__((address_space(1))) void*)g,
        (__attribute__((address_space(3))) void*)l, 16, 0, 0);
}
// Stage one 8KB plane (64 rows x 128B) with XOR-preswizzled source.
__device__ __forceinline__ void stage8k(const char* g, size_t rstrideB,
                                        char* ldsPlane, int w, int lane) {
    int r = w * 8 + (lane >> 3);
    int cs = (lane & 7) ^ (r & 7);
    gload16(g + (size_t)r * rstrideB + cs * 16, ldsPlane + (size_t)w * 1024);
}
#define SBAR() { __builtin_amdgcn_sched_barrier(0); \
    __builtin_amdgcn_s_barrier(); __builtin_amdgcn_sched_barrier(0); }

// ---------------------------------------------------------------------------
// cvt_w: all four weight matrices f32 -> bf16 (hi only).
// ---------------------------------------------------------------------------
__global__ __launch_bounds__(256)
void cvt_w(const float* __restrict__ Wq, const float* __restrict__ Wk,
           const float* __restrict__ Wv, const float* __restrict__ Wo,
           u16* __restrict__ Wqh, u16* __restrict__ Wkh,
           u16* __restrict__ Wvh, u16* __restrict__ Woh) {
    int bid = blockIdx.x;
    const float* src; u16* dh;
    if (bid < 512)       { src = Wq; dh = Wqh; }
    else if (bid < 1024) { bid -= 512;  src = Wk; dh = Wkh; }
    else if (bid < 1536) { bid -= 1024; src = Wv; dh = Wvh; }
    else                 { bid -= 1536; src = Wo; dh = Woh; }
    size_t i = ((size_t)bid * 256 + threadIdx.x) * 8;
    float4 a = *(const float4*)&src[i];
    float4 b = *(const float4*)&src[i + 4];
    float v[8] = {a.x, a.y, a.z, a.w, b.x, b.y, b.z, b.w};
    u16x8 hi;
#pragma unroll
    for (int j = 0; j < 8; ++j) hi[j] = f2bf(v[j]);
    *(u16x8*)&dh[i] = hi;
}

// ---------------------------------------------------------------------------
// GEMM NT: Y = A * W^T + bias. K=1024. 128x128 tile, 2-deep register
// prefetch. AMODE: 0 = A f32 (cvt at write), 1 = A bf16 direct.
// WMODE: 0 = W f32 (cvt), 1 = W bf16 direct.
// OUT_MODE 0: f32 + bias[col]. 4: bf16 V^T head-major (+bias[row]).
// 5: bf16 head-major (+bias[col]). 6: mode 5 scaled by PSC (Q projection).
// ---------------------------------------------------------------------------
#define GEMM_LOAD(S, kk) { \
    if constexpr (AMODE == 0) { \
        _Pragma("unroll") for (int j = 0; j < 4; ++j) \
            *(float4*)&ax##S[j * 4] = *(const float4*)&Af[(size_t)(rowBase + srow) * 1024 + (kk) + sc + j * 4]; \
    } else { \
        au##S##0 = *(const u16x8*)&Au[(size_t)(rowBase + srow) * 1024 + (kk) + sc]; \
        au##S##1 = *(const u16x8*)&Au[(size_t)(rowBase + srow) * 1024 + (kk) + sc + 8]; \
    } \
    if constexpr (WMODE == 0) { \
        _Pragma("unroll") for (int j = 0; j < 4; ++j) \
            *(float4*)&bx##S[j * 4] = *(const float4*)&Wf[(size_t)(colBase + srow) * 1024 + (kk) + sc + j * 4]; \
    } else { \
        wh##S##0 = *(const u16x8*)&Wu[(size_t)(colBase + srow) * 1024 + (kk) + sc]; \
        wh##S##1 = *(const u16x8*)&Wu[(size_t)(colBase + srow) * 1024 + (kk) + sc + 8]; \
    } }

#define GEMM_WRITE(S) { \
    u16x8 h0, h1; \
    if constexpr (AMODE == 0) { \
        _Pragma("unroll") for (int j = 0; j < 8; ++j) { \
            h0[j] = f2bf(ax##S[j]); h1[j] = f2bf(ax##S[j + 8]); } \
    } else { h0 = au##S##0; h1 = au##S##1; } \
    *(u16x8*)&sA[srow * 40 + sc] = h0; \
    *(u16x8*)&sA[srow * 40 + sc + 8] = h1; \
    u16x8 b0, b1; \
    if constexpr (WMODE == 0) { \
        _Pragma("unroll") for (int j = 0; j < 8; ++j) { \
            b0[j] = f2bf(bx##S[j]); b1[j] = f2bf(bx##S[j + 8]); } \
    } else { b0 = wh##S##0; b1 = wh##S##1; } \
    *(u16x8*)&sB[srow * 40 + sc] = b0; \
    *(u16x8*)&sB[srow * 40 + sc + 8] = b1; }

#define GEMM_COMPUTE() { \
    s16x8 afh[4], bfh[4]; \
    _Pragma("unroll") for (int mi = 0; mi < 4; ++mi) { \
        int ai = (wm * 64 + mi * 16 + (lane & 15)) * 40 + (lane >> 4) * 8; \
        afh[mi] = *(const s16x8*)&sA[ai]; \
    } \
    _Pragma("unroll") for (int ni = 0; ni < 4; ++ni) { \
        int bi = (wn * 64 + ni * 16 + (lane & 15)) * 40 + (lane >> 4) * 8; \
        bfh[ni] = *(const s16x8*)&sB[bi]; \
    } \
    _Pragma("unroll") for (int mi = 0; mi < 4; ++mi) \
        _Pragma("unroll") for (int ni = 0; ni < 4; ++ni) \
            acc[mi][ni] = mfma16(afh[mi], bfh[ni], acc[mi][ni]); }

template<int AMODE, int WMODE, int OUT_MODE>
__global__ __launch_bounds__(256)
void gemm_mfma(const void* __restrict__ Ap, const void* __restrict__ Wop,
               const float* __restrict__ bias, void* __restrict__ Y0p,
               int M, int N, int bshift) {
    __shared__ u16 sA[128 * 40];
    __shared__ u16 sB[128 * 40];

    const int t = threadIdx.x;
    const int lane = t & 63;
    const int w = t >> 6;
    const int wm = w >> 1, wn = w & 1;
    const int rowBase = blockIdx.y * 128;
    const int colBase = blockIdx.x * 128;
    const int srow = t >> 1;
    const int sc = (t & 1) * 16;

    const float* Af = (const float*)Ap;
    const u16* Au = (const u16*)Ap;
    const float* Wf = (const float*)Wop;
    const u16* Wu = (const u16*)Wop;

    f32x4 acc[4][4];
#pragma unroll
    for (int i = 0; i < 4; ++i)
#pragma unroll
        for (int j = 0; j < 4; ++j) acc[i][j] = (f32x4){0.f, 0.f, 0.f, 0.f};

    float ax0[16], ax1[16], bx0[16], bx1[16];
    u16x8 au00, au01, au10, au11;
    u16x8 wh00, wh01, wh10, wh11;

    GEMM_LOAD(0, 0)
    GEMM_LOAD(1, 32)

    for (int k0 = 0; k0 < 1024; k0 += 64) {
        __syncthreads();
        GEMM_WRITE(0)
        __syncthreads();
        if (k0 + 64 < 1024) GEMM_LOAD(0, k0 + 64)
        GEMM_COMPUTE()
        __syncthreads();
        GEMM_WRITE(1)
        __syncthreads();
        if (k0 + 96 < 1024) GEMM_LOAD(1, k0 + 96)
        GEMM_COMPUTE()
    }

#pragma unroll
    for (int mi = 0; mi < 4; ++mi)
#pragma unroll
        for (int ni = 0; ni < 4; ++ni)
#pragma unroll
            for (int rr = 0; rr < 4; ++rr) {
                int mg = rowBase + wm * 64 + mi * 16 + (lane >> 4) * 4 + rr;
                int ng = colBase + wn * 64 + ni * 16 + (lane & 15);
                float y = acc[mi][ni][rr];
                if constexpr (OUT_MODE == 0) {
                    ((float*)Y0p)[(size_t)mg * N + ng] = y + bias[ng];
                } else if constexpr (OUT_MODE == 4) {
                    y += bias[mg];
                    size_t idx = ((size_t)((ng >> 11) * 16 + (mg >> 6)) * 64 + (mg & 63)) * 2048 + (ng & 2047);
                    ((u16*)Y0p)[idx] = f2bf(y);
                } else if constexpr (OUT_MODE == 5 || OUT_MODE == 6) {
                    y += bias[ng];
                    if constexpr (OUT_MODE == 6) y *= PSC;
                    int bb = mg >> bshift, s = mg & ((1 << bshift) - 1);
                    size_t idx = ((((size_t)(bb * 16 + (ng >> 6))) << bshift) + s) * 64 + (ng & 63);
                    ((u16*)Y0p)[idx] = f2bf(y);
                }
            }
}

// ---------------------------------------------------------------------------
// Pass 1: attended output + denominators. Q pre-scaled by PSC -> e = exp2(s).
// l via ones-A-fragment MFMA. K/V now 4-deep buffered with counted vmcnt(4)
// (prefetch distance 3 chunks; tail drains 4->2->0). setprio(1) around the
// MFMA+exp cluster (T5).
// ---------------------------------------------------------------------------
__global__ __launch_bounds__(512, 4)
void attn_O(const u16* __restrict__ Qhi, const u16* __restrict__ Khi,
            const u16* __restrict__ VT, u16* __restrict__ Att,
            float* __restrict__ llog) {
    __shared__ char lds[65536];
    // staging: K bufs 4x8K @0; V bufs 4x8K @32768.
    // epilogue (after final barrier): sOf f32[2][64][68] @0; sL2 @35840.
    float* sOf = (float*)lds;
    float* sL2 = (float*)(lds + 35840);

    const int t = threadIdx.x;
    const int w = t >> 6, lane = t & 63;
    const int g = lane >> 4, c16 = lane & 15;
    const int qt = blockIdx.x >> 6;
    const int g6 = blockIdx.x & 63;
    const int b = g6 >> 4, h = g6 & 15;
    const int qbase = qt * 128;
    const int wq = w >> 1, wk = w & 1;
    const int kswz = (g ^ (c16 & 7)) << 4;
    const int vsw0 = (((wk * 4 + 0 + (g >> 1)) ^ (c16 & 7)) << 4) | ((g & 1) << 3);
    const int vsw1 = (((wk * 4 + 2 + (g >> 1)) ^ (c16 & 7)) << 4) | ((g & 1) << 3);

    const char* Kh_g = (const char*)(Khi + (size_t)(b * 16 + h) * SKL * 64);
    const char* V_g  = (const char*)(VT + (size_t)(b * 16 + h) * 64 * SKL);

    s16x8 qh[2][2];
    const size_t qrowbase = (size_t)(b * 16 + h) * SQL + qbase;
#pragma unroll
    for (int qf = 0; qf < 2; ++qf) {
        size_t qo = (qrowbase + wq * 32 + qf * 16 + c16) * 64 + g * 8;
        qh[qf][0] = *(const s16x8*)&Qhi[qo];
        qh[qf][1] = *(const s16x8*)&Qhi[qo + 32];
    }

    // prologue: chunks 0..2 (K,V interleaved per chunk -- vmcnt order matters)
#pragma unroll
    for (int i = 0; i < 3; ++i) {
        stage8k(Kh_g + (size_t)i * 8192, 128, lds + i * 8192, w, lane);
        stage8k(V_g + (size_t)i * 128, 4096, lds + 32768 + i * 8192, w, lane);
    }

    const s16x4 onesf = {(short)0x3F80, (short)0x3F80, (short)0x3F80, (short)0x3F80};
    f32x4 oacc[2][4];
    f32x4 lacc[2];
#pragma unroll
    for (int qf = 0; qf < 2; ++qf) {
        lacc[qf] = (f32x4){0.f, 0.f, 0.f, 0.f};
#pragma unroll
        for (int i = 0; i < 4; ++i) oacc[qf][i] = (f32x4){0.f, 0.f, 0.f, 0.f};
    }

    for (int c = 0; c < 32; ++c) {
        if (c < 30)       { asm volatile("s_waitcnt vmcnt(4)" ::: "memory"); }
        else if (c == 30) { asm volatile("s_waitcnt vmcnt(2)" ::: "memory"); }
        else              { asm volatile("s_waitcnt vmcnt(0)" ::: "memory"); }
        SBAR();
        if (c + 3 < 32) {
            int nb = (c + 3) & 3;   // buffer held chunk c-1, consumed last iter
            stage8k(Kh_g + (size_t)(c + 3) * 8192, 128, lds + nb * 8192, w, lane);
            stage8k(V_g + (size_t)(c + 3) * 128, 4096, lds + 32768 + nb * 8192, w, lane);
        }
        char* curK = lds + (c & 3) * 8192;
        char* curV = lds + 32768 + (c & 3) * 8192;
        __builtin_amdgcn_s_setprio(1);
#pragma unroll
        for (int kf = 0; kf < 2; ++kf) {
            int kb = (wk * 32 + kf * 16 + c16) * 128 + kswz;
            s16x8 kh0 = *(const s16x8*)(curK + kb);
            s16x8 kh1 = *(const s16x8*)(curK + (kb ^ 64));
            s16x4 pb[2];
#pragma unroll
            for (int qf = 0; qf < 2; ++qf) {
                f32x4 s = {0.f, 0.f, 0.f, 0.f};
                s = mfma16(kh0, qh[qf][0], s);
                s = mfma16(kh1, qh[qf][1], s);
                pb[qf][0] = (short)f2bf(exp2f(s[0]));
                pb[qf][1] = (short)f2bf(exp2f(s[1]));
                pb[qf][2] = (short)f2bf(exp2f(s[2]));
                pb[qf][3] = (short)f2bf(exp2f(s[3]));
                lacc[qf] = mfma16k16(onesf, pb[qf], lacc[qf]);
            }
            int vs = kf ? vsw1 : vsw0;
#pragma unroll
            for (int df = 0; df < 4; ++df) {
                s16x4 vf = *(const s16x4*)(curV + (df * 16 + c16) * 128 + vs);
                oacc[0][df] = mfma16k16(vf, pb[0], oacc[0][df]);
                oacc[1][df] = mfma16k16(vf, pb[1], oacc[1][df]);
            }
        }
        __builtin_amdgcn_s_setprio(0);
    }

    __syncthreads();   // all compute done; staging region becomes sOf
#pragma unroll
    for (int qf = 0; qf < 2; ++qf)
        if (g == 0) sL2[wk * 128 + wq * 32 + qf * 16 + c16] = lacc[qf][0];

#pragma unroll
    for (int half = 0; half < 2; ++half) {
        if (half) __syncthreads();
        if ((wq >> 1) == half) {
            int qlocal = (wq & 1) * 32 + c16;
#pragma unroll
            for (int qf = 0; qf < 2; ++qf)
#pragma unroll
                for (int df = 0; df < 4; ++df)
#pragma unroll
                    for (int r = 0; r < 4; ++r)
                        sOf[wk * 4352 + (df * 16 + g * 4 + r) * 68 + qlocal + qf * 16] =
                            oacc[qf][df][r];
        }
        __syncthreads();
        {
            int q = t >> 3, dg = t & 7;
            float l = sL2[half * 64 + q] + sL2[128 + half * 64 + q];
            float linv = 1.f / l;
            u16x8 ov;
#pragma unroll
            for (int i = 0; i < 8; ++i) {
                int d = dg * 8 + i;
                ov[i] = f2bf((sOf[d * 68 + q] + sOf[4352 + d * 68 + q]) * linv);
            }
            *(u16x8*)&Att[(size_t)(b * SQL + qbase + half * 64 + q) * EMBED + h * 64 + dg * 8] = ov;
            if (dg == 0)
                llog[(size_t)(b * 16 + h) * SQL + qbase + half * 64 + q] = log2f(l);
        }
    }
}

// ---------------------------------------------------------------------------
// Pass 2: mean_attn (Q pre-scaled: p = exp2(s - lb)). r14 structure +
// setprio around the compute cluster.
// ---------------------------------------------------------------------------
__global__ __launch_bounds__(512, 4)
void attn_mean(const u16* __restrict__ Qhi, const u16* __restrict__ Khi,
               const float* __restrict__ llog, float* __restrict__ meanOut) {
    __shared__ char lds[81920];   // Q dbuf 2x16K @0; K tbuf 3x16K @32768

    const int t = threadIdx.x;
    const int w = t >> 6, lane = t & 63;
    const int g = lane >> 4, c16 = lane & 15;
    const int qt = blockIdx.x >> 6;
    const int low = blockIdx.x & 63;
    const int b = low >> 4, ks = low & 15;
    const int qbase = qt * 128;
    const int kbase = ks * 128;
    const int wq = w >> 1, wk = w & 1;
    const int kswz = (g ^ (c16 & 7)) << 4;

    const size_t QH_STRIDE = (size_t)SQL * 128;
    const size_t KH_STRIDE = (size_t)SKL * 128;
    const char* Qh_b = (const char*)(Qhi + ((size_t)(b * 16) * SQL + qbase) * 64);
    const char* Kh_b = (const char*)(Khi + ((size_t)(b * 16) * SKL + kbase) * 64);
    const float* ll_b = llog + (size_t)(b * 16) * SQL + qbase;

    f32x4 ma[2][4];
#pragma unroll
    for (int qf = 0; qf < 2; ++qf)
#pragma unroll
        for (int i = 0; i < 4; ++i) ma[qf][i] = (f32x4){0.f, 0.f, 0.f, 0.f};

    stage8k(Qh_b, 128, lds, w, lane);
    stage8k(Qh_b + 8192, 128, lds + 8192, w, lane);
    float lbA0 = ll_b[wq * 32 + c16];
    float lbA1 = ll_b[wq * 32 + 16 + c16];
    stage8k(Kh_b, 128, lds + 32768, w, lane);
    stage8k(Kh_b + 8192, 128, lds + 32768 + 8192, w, lane);
    stage8k(Qh_b + QH_STRIDE, 128, lds + 16384, w, lane);
    stage8k(Qh_b + QH_STRIDE + 8192, 128, lds + 16384 + 8192, w, lane);
    float lbB0 = ll_b[SQL + wq * 32 + c16];
    float lbB1 = ll_b[SQL + wq * 32 + 16 + c16];
    stage8k(Kh_b + KH_STRIDE, 128, lds + 32768 + 16384, w, lane);
    stage8k(Kh_b + KH_STRIDE + 8192, 128, lds + 32768 + 16384 + 8192, w, lane);

    int curK = 0;
    for (int h = 0; h < 16; ++h) {
        if (h < 15) { asm volatile("s_waitcnt vmcnt(4)" ::: "memory"); }
        else        { asm volatile("s_waitcnt vmcnt(0)" ::: "memory"); }
        SBAR();

        const char* sQ = lds + (h & 1) * 16384;
        s16x8 qa0, qa1, qc0, qc1;
        {
            int qb0 = (wq * 32 + c16) * 128 + kswz;
            qa0 = *(const s16x8*)(sQ + qb0);
            qa1 = *(const s16x8*)(sQ + (qb0 ^ 64));
            int qb1 = (wq * 32 + 16 + c16) * 128 + kswz;
            qc0 = *(const s16x8*)(sQ + qb1);
            qc1 = *(const s16x8*)(sQ + (qb1 ^ 64));
        }
        asm volatile("s_waitcnt lgkmcnt(0)" ::: "memory");
        SBAR();

        float lb0 = lbA0, lb1 = lbA1;
        lbA0 = lbB0; lbA1 = lbB1;

        if (h + 2 < 16) {
            const char* Qg = Qh_b + (size_t)(h + 2) * QH_STRIDE;
            char* qdst = lds + (h & 1) * 16384;
            stage8k(Qg, 128, qdst, w, lane);
            stage8k(Qg + 8192, 128, qdst + 8192, w, lane);
            lbB0 = ll_b[(size_t)(h + 2) * SQL + wq * 32 + c16];
            lbB1 = ll_b[(size_t)(h + 2) * SQL + wq * 32 + 16 + c16];
            const char* Kg = Kh_b + (size_t)(h + 2) * KH_STRIDE;
            int nb = curK + 2; if (nb >= 3) nb -= 3;
            char* kdst = lds + 32768 + nb * 16384;
            stage8k(Kg, 128, kdst, w, lane);
            stage8k(Kg + 8192, 128, kdst + 8192, w, lane);
        }

        const char* sK = lds + 32768 + curK * 16384;
        __builtin_amdgcn_s_setprio(1);
#pragma unroll
        for (int kf = 0; kf < 4; ++kf) {
            int kb = (kf * 32 + wk * 16 + c16) * 128 + kswz;
            s16x8 kh0 = *(const s16x8*)(sK + kb);
            s16x8 kh1 = *(const s16x8*)(sK + (kb ^ 64));
            {
                f32x4 s = {0.f, 0.f, 0.f, 0.f};
                s = mfma16(kh0, qa0, s);
                s = mfma16(kh1, qa1, s);
                ma[0][kf][0] += exp2f(s[0] - lb0);
                ma[0][kf][1] += exp2f(s[1] - lb0);
                ma[0][kf][2] += exp2f(s[2] - lb0);
                ma[0][kf][3] += exp2f(s[3] - lb0);
            }
            {
                f32x4 s = {0.f, 0.f, 0.f, 0.f};
                s = mfma16(kh0, qc0, s);
                s = mfma16(kh1, qc1, s);
                ma[1][kf][0] += exp2f(s[0] - lb1);
                ma[1][kf][1] += exp2f(s[1] - lb1);
                ma[1][kf][2] += exp2f(s[2] - lb1);
                ma[1][kf][3] += exp2f(s[3] - lb1);
            }
        }
        __builtin_amdgcn_s_setprio(0);
        ++curK; if (curK == 3) curK = 0;
    }

    const float s16c = 1.f / 16.f;
#pragma unroll
    for (int qf = 0; qf < 2; ++qf)
#pragma unroll
        for (int kf = 0; kf < 4; ++kf) {
            f32x4 m = ma[qf][kf];
            m[0] *= s16c; m[1] *= s16c; m[2] *= s16c; m[3] *= s16c;
            *(f32x4*)&meanOut[(size_t)(b * SQL + qbase + wq * 32 + qf * 16 + c16) * SKL +
                              kbase + kf * 32 + wk * 16 + g * 4] = m;
        }
}

// ---------------------------------------------------------------------------
extern "C" void kernel_launch(void* const* d_in, const int* in_sizes, int n_in,
                              void* d_out, int out_size, void* d_ws, size_t ws_size,
                              hipStream_t stream) {
    const float* query = (const float*)d_in[0];
    const float* key   = (const float*)d_in[1];
    const float* value = (const float*)d_in[2];
    const float* Wq = (const float*)d_in[3];
    const float* bq = (const float*)d_in[4];
    const float* Wk = (const float*)d_in[5];
    const float* bk = (const float*)d_in[6];
    const float* Wv = (const float*)d_in[7];
    const float* bv = (const float*)d_in[8];
    const float* Wo = (const float*)d_in[9];
    const float* bo = (const float*)d_in[10];

    float* out = (float*)d_out;                         // [4,1024,1024] f32
    float* meanOut = out + (size_t)BATCH * SQL * EMBED; // [4,1024,2048] f32

    u16* Qhi = (u16*)d_ws;                              // head-major [b][h][q][64], pre-scaled by PSC
    u16* Khi = Qhi + (size_t)4096 * 1024;               // [b][h][k][64]
    u16* VTh = Khi + (size_t)8192 * 1024;               // [b][h][d][2048]
    u16* Att = VTh + (size_t)8192 * 1024;               // [4096][1024] bf16
    float* llog = (float*)(Att + (size_t)4096 * 1024);  // [b*16+h][q]
    u16* Wqh = (u16*)(llog + 64 * 1024);                // bf16 weight planes
    u16* Wkh = Wqh + (size_t)1024 * 1024;
    u16* Wvh = Wkh + (size_t)1024 * 1024;
    u16* Woh = Wvh + (size_t)1024 * 1024;

    cvt_w<<<dim3(2048), 256, 0, stream>>>(Wq, Wk, Wv, Wo, Wqh, Wkh, Wvh, Woh);

    gemm_mfma<0, 1, 6><<<dim3(8, 32), 256, 0, stream>>>(query, Wqh, bq, Qhi, 4096, 1024, 10);
    gemm_mfma<0, 1, 5><<<dim3(8, 64), 256, 0, stream>>>(key, Wkh, bk, Khi, 8192, 1024, 11);
    gemm_mfma<1, 0, 4><<<dim3(64, 8), 256, 0, stream>>>(Wvh, value, bv, VTh, 1024, 8192, 0);

    attn_O<<<dim3(512), dim3(512), 0, stream>>>(Qhi, Khi, VTh, Att, llog);
    attn_mean<<<dim3(512), dim3(512), 0, stream>>>(Qhi, Khi, llog, meanOut);

    gemm_mfma<1, 1, 0><<<dim3(8, 32), 256, 0, stream>>>(Att, Woh, bo, out, 4096, 1024, 0);
}

// Round 17
// 229.216 us; speedup vs baseline: 1.0113x; 1.0113x over previous
//
#include <hip/hip_runtime.h>
#include <hip/hip_bf16.h>
#include <math.h>

#define EMBED 1024
#define NHEADS 16
#define HDIM 64
#define BATCH 4
#define SQL 1024
#define SKL 2048
#define PSC 0.18033688f   // 0.125 * log2(e)  (folded into Q projection)

typedef unsigned short u16;
typedef __attribute__((ext_vector_type(4))) float f32x4;
typedef __attribute__((ext_vector_type(8))) __bf16 bf16x8;
typedef __attribute__((ext_vector_type(8))) short s16x8;
typedef __attribute__((ext_vector_type(4))) short s16x4;
typedef __attribute__((ext_vector_type(8))) u16 u16x8;
typedef __attribute__((ext_vector_type(2))) unsigned u32x2;

__device__ __forceinline__ u16 f2bf(float x) {
    __hip_bfloat16 h = __float2bfloat16(x);
    return *reinterpret_cast<u16*>(&h);
}
__device__ __forceinline__ float bf2f(u16 u) {
    __hip_bfloat16 h;
    *reinterpret_cast<u16*>(&h) = u;
    return __bfloat162float(h);
}
// Truncation-pack: {bf16_trunc(e1), bf16_trunc(e0)} in one v_perm_b32.
// Safe for positive finite values (p = exp2(s)); bias cancels in O = num/den
// because numerator and denominator use the same truncated p.
__device__ __forceinline__ unsigned permpack(float e0, float e1) {
    return __builtin_amdgcn_perm(__builtin_bit_cast(unsigned, e1),
                                 __builtin_bit_cast(unsigned, e0), 0x07060302u);
}
__device__ __forceinline__ f32x4 mfma16(s16x8 a, s16x8 b, f32x4 c) {
    return __builtin_amdgcn_mfma_f32_16x16x32_bf16(
        __builtin_bit_cast(bf16x8, a), __builtin_bit_cast(bf16x8, b), c, 0, 0, 0);
}
__device__ __forceinline__ f32x4 mfma16k16(s16x4 a, s16x4 b, f32x4 c) {
    return __builtin_amdgcn_mfma_f32_16x16x16bf16_1k(a, b, c, 0, 0, 0);
}
__device__ __forceinline__ void gload16(const void* g, void* l) {
    __builtin_amdgcn_global_load_lds(
        (const __attribute__((address_space(1))) void*)g,
        (__attribute__((address_space(3))) void*)l, 16, 0, 0);
}
// Stage one 8KB plane (64 rows x 128B) with XOR-preswizzled source.
__device__ __forceinline__ void stage8k(const char* g, size_t rstrideB,
                                        char* ldsPlane, int w, int lane) {
    int r = w * 8 + (lane >> 3);
    int cs = (lane & 7) ^ (r & 7);
    gload16(g + (size_t)r * rstrideB + cs * 16, ldsPlane + (size_t)w * 1024);
}
#define SBAR() { __builtin_amdgcn_sched_barrier(0); \
    __builtin_amdgcn_s_barrier(); __builtin_amdgcn_sched_barrier(0); }

// ---------------------------------------------------------------------------
// cvt_w: all four weight matrices f32 -> bf16 (hi only, RNE).
// ---------------------------------------------------------------------------
__global__ __launch_bounds__(256)
void cvt_w(const float* __restrict__ Wq, const float* __restrict__ Wk,
           const float* __restrict__ Wv, const float* __restrict__ Wo,
           u16* __restrict__ Wqh, u16* __restrict__ Wkh,
           u16* __restrict__ Wvh, u16* __restrict__ Woh) {
    int bid = blockIdx.x;
    const float* src; u16* dh;
    if (bid < 512)       { src = Wq; dh = Wqh; }
    else if (bid < 1024) { bid -= 512;  src = Wk; dh = Wkh; }
    else if (bid < 1536) { bid -= 1024; src = Wv; dh = Wvh; }
    else                 { bid -= 1536; src = Wo; dh = Woh; }
    size_t i = ((size_t)bid * 256 + threadIdx.x) * 8;
    float4 a = *(const float4*)&src[i];
    float4 b = *(const float4*)&src[i + 4];
    float v[8] = {a.x, a.y, a.z, a.w, b.x, b.y, b.z, b.w};
    u16x8 hi;
#pragma unroll
    for (int j = 0; j < 8; ++j) hi[j] = f2bf(v[j]);
    *(u16x8*)&dh[i] = hi;
}

// ---------------------------------------------------------------------------
// GEMM NT: Y = A * W^T + bias. K=1024. 128x128 tile, 2-deep register
// prefetch. AMODE: 0 = A f32 (cvt at write), 1 = A bf16 direct.
// WMODE: 0 = W f32 (cvt), 1 = W bf16 direct.
// OUT_MODE 0: f32 + bias[col]. 4: bf16 V^T head-major (+bias[row]).
// 5: bf16 head-major (+bias[col]). 6: mode 5 scaled by PSC (Q projection).
// ---------------------------------------------------------------------------
#define GEMM_LOAD(S, kk) { \
    if constexpr (AMODE == 0) { \
        _Pragma("unroll") for (int j = 0; j < 4; ++j) \
            *(float4*)&ax##S[j * 4] = *(const float4*)&Af[(size_t)(rowBase + srow) * 1024 + (kk) + sc + j * 4]; \
    } else { \
        au##S##0 = *(const u16x8*)&Au[(size_t)(rowBase + srow) * 1024 + (kk) + sc]; \
        au##S##1 = *(const u16x8*)&Au[(size_t)(rowBase + srow) * 1024 + (kk) + sc + 8]; \
    } \
    if constexpr (WMODE == 0) { \
        _Pragma("unroll") for (int j = 0; j < 4; ++j) \
            *(float4*)&bx##S[j * 4] = *(const float4*)&Wf[(size_t)(colBase + srow) * 1024 + (kk) + sc + j * 4]; \
    } else { \
        wh##S##0 = *(const u16x8*)&Wu[(size_t)(colBase + srow) * 1024 + (kk) + sc]; \
        wh##S##1 = *(const u16x8*)&Wu[(size_t)(colBase + srow) * 1024 + (kk) + sc + 8]; \
    } }

#define GEMM_WRITE(S) { \
    u16x8 h0, h1; \
    if constexpr (AMODE == 0) { \
        _Pragma("unroll") for (int j = 0; j < 8; ++j) { \
            h0[j] = f2bf(ax##S[j]); h1[j] = f2bf(ax##S[j + 8]); } \
    } else { h0 = au##S##0; h1 = au##S##1; } \
    *(u16x8*)&sA[srow * 40 + sc] = h0; \
    *(u16x8*)&sA[srow * 40 + sc + 8] = h1; \
    u16x8 b0, b1; \
    if constexpr (WMODE == 0) { \
        _Pragma("unroll") for (int j = 0; j < 8; ++j) { \
            b0[j] = f2bf(bx##S[j]); b1[j] = f2bf(bx##S[j + 8]); } \
    } else { b0 = wh##S##0; b1 = wh##S##1; } \
    *(u16x8*)&sB[srow * 40 + sc] = b0; \
    *(u16x8*)&sB[srow * 40 + sc + 8] = b1; }

#define GEMM_COMPUTE() { \
    s16x8 afh[4], bfh[4]; \
    _Pragma("unroll") for (int mi = 0; mi < 4; ++mi) { \
        int ai = (wm * 64 + mi * 16 + (lane & 15)) * 40 + (lane >> 4) * 8; \
        afh[mi] = *(const s16x8*)&sA[ai]; \
    } \
    _Pragma("unroll") for (int ni = 0; ni < 4; ++ni) { \
        int bi = (wn * 64 + ni * 16 + (lane & 15)) * 40 + (lane >> 4) * 8; \
        bfh[ni] = *(const s16x8*)&sB[bi]; \
    } \
    _Pragma("unroll") for (int mi = 0; mi < 4; ++mi) \
        _Pragma("unroll") for (int ni = 0; ni < 4; ++ni) \
            acc[mi][ni] = mfma16(afh[mi], bfh[ni], acc[mi][ni]); }

template<int AMODE, int WMODE, int OUT_MODE>
__global__ __launch_bounds__(256)
void gemm_mfma(const void* __restrict__ Ap, const void* __restrict__ Wop,
               const float* __restrict__ bias, void* __restrict__ Y0p,
               int M, int N, int bshift) {
    __shared__ u16 sA[128 * 40];
    __shared__ u16 sB[128 * 40];

    const int t = threadIdx.x;
    const int lane = t & 63;
    const int w = t >> 6;
    const int wm = w >> 1, wn = w & 1;
    const int rowBase = blockIdx.y * 128;
    const int colBase = blockIdx.x * 128;
    const int srow = t >> 1;
    const int sc = (t & 1) * 16;

    const float* Af = (const float*)Ap;
    const u16* Au = (const u16*)Ap;
    const float* Wf = (const float*)Wop;
    const u16* Wu = (const u16*)Wop;

    f32x4 acc[4][4];
#pragma unroll
    for (int i = 0; i < 4; ++i)
#pragma unroll
        for (int j = 0; j < 4; ++j) acc[i][j] = (f32x4){0.f, 0.f, 0.f, 0.f};

    float ax0[16], ax1[16], bx0[16], bx1[16];
    u16x8 au00, au01, au10, au11;
    u16x8 wh00, wh01, wh10, wh11;

    GEMM_LOAD(0, 0)
    GEMM_LOAD(1, 32)

    for (int k0 = 0; k0 < 1024; k0 += 64) {
        __syncthreads();
        GEMM_WRITE(0)
        __syncthreads();
        if (k0 + 64 < 1024) GEMM_LOAD(0, k0 + 64)
        GEMM_COMPUTE()
        __syncthreads();
        GEMM_WRITE(1)
        __syncthreads();
        if (k0 + 96 < 1024) GEMM_LOAD(1, k0 + 96)
        GEMM_COMPUTE()
    }

#pragma unroll
    for (int mi = 0; mi < 4; ++mi)
#pragma unroll
        for (int ni = 0; ni < 4; ++ni)
#pragma unroll
            for (int rr = 0; rr < 4; ++rr) {
                int mg = rowBase + wm * 64 + mi * 16 + (lane >> 4) * 4 + rr;
                int ng = colBase + wn * 64 + ni * 16 + (lane & 15);
                float y = acc[mi][ni][rr];
                if constexpr (OUT_MODE == 0) {
                    ((float*)Y0p)[(size_t)mg * N + ng] = y + bias[ng];
                } else if constexpr (OUT_MODE == 4) {
                    y += bias[mg];
                    size_t idx = ((size_t)((ng >> 11) * 16 + (mg >> 6)) * 64 + (mg & 63)) * 2048 + (ng & 2047);
                    ((u16*)Y0p)[idx] = f2bf(y);
                } else if constexpr (OUT_MODE == 5 || OUT_MODE == 6) {
                    y += bias[ng];
                    if constexpr (OUT_MODE == 6) y *= PSC;
                    int bb = mg >> bshift, s = mg & ((1 << bshift) - 1);
                    size_t idx = ((((size_t)(bb * 16 + (ng >> 6))) << bshift) + s) * 64 + (ng & 63);
                    ((u16*)Y0p)[idx] = f2bf(y);
                }
            }
}

// ---------------------------------------------------------------------------
// Pass 1: attended output + denominators. Q pre-scaled by PSC -> e = exp2(s).
// p packed by TRUNCATION via v_perm_b32 (1 instr / 2 values); O's numerator
// and denominator (ones-MFMA lacc) share the same truncated p so the bias
// cancels. llog uses a separate f32 lsum (unbiased, matches attn_mean's f32
// exp2 sums). K/V triple-buffered, counted vmcnt(2).  (r14 sync structure.)
// ---------------------------------------------------------------------------
__global__ __launch_bounds__(512, 4)
void attn_O(const u16* __restrict__ Qhi, const u16* __restrict__ Khi,
            const u16* __restrict__ VT, u16* __restrict__ Att,
            float* __restrict__ llog) {
    __shared__ char lds[49152];
    // staging: K bufs 3x8K @0; V bufs 3x8K @24576.
    // epilogue: sOf f32[2][64][68] @0; sL2t @35840; sL2f @36864.
    float* sOf = (float*)lds;
    float* sL2t = (float*)(lds + 35840);
    float* sL2f = (float*)(lds + 36864);

    const int t = threadIdx.x;
    const int w = t >> 6, lane = t & 63;
    const int g = lane >> 4, c16 = lane & 15;
    const int qt = blockIdx.x >> 6;
    const int g6 = blockIdx.x & 63;
    const int b = g6 >> 4, h = g6 & 15;
    const int qbase = qt * 128;
    const int wq = w >> 1, wk = w & 1;
    const int kswz = (g ^ (c16 & 7)) << 4;
    const int vsw0 = (((wk * 4 + 0 + (g >> 1)) ^ (c16 & 7)) << 4) | ((g & 1) << 3);
    const int vsw1 = (((wk * 4 + 2 + (g >> 1)) ^ (c16 & 7)) << 4) | ((g & 1) << 3);

    const char* Kh_g = (const char*)(Khi + (size_t)(b * 16 + h) * SKL * 64);
    const char* V_g  = (const char*)(VT + (size_t)(b * 16 + h) * 64 * SKL);

    s16x8 qh[2][2];
    const size_t qrowbase = (size_t)(b * 16 + h) * SQL + qbase;
#pragma unroll
    for (int qf = 0; qf < 2; ++qf) {
        size_t qo = (qrowbase + wq * 32 + qf * 16 + c16) * 64 + g * 8;
        qh[qf][0] = *(const s16x8*)&Qhi[qo];
        qh[qf][1] = *(const s16x8*)&Qhi[qo + 32];
    }

    stage8k(Kh_g, 128, lds, w, lane);
    stage8k(V_g, 4096, lds + 24576, w, lane);
    stage8k(Kh_g + 8192, 128, lds + 8192, w, lane);
    stage8k(V_g + 128, 4096, lds + 24576 + 8192, w, lane);

    const s16x4 onesf = {(short)0x3F80, (short)0x3F80, (short)0x3F80, (short)0x3F80};
    f32x4 oacc[2][4];
    f32x4 lacc[2];
    float lsum[2] = {0.f, 0.f};
#pragma unroll
    for (int qf = 0; qf < 2; ++qf) {
        lacc[qf] = (f32x4){0.f, 0.f, 0.f, 0.f};
#pragma unroll
        for (int i = 0; i < 4; ++i) oacc[qf][i] = (f32x4){0.f, 0.f, 0.f, 0.f};
    }

    int cur = 0;
    for (int c = 0; c < 32; ++c) {
        if (c < 31) { asm volatile("s_waitcnt vmcnt(2)" ::: "memory"); }
        else        { asm volatile("s_waitcnt vmcnt(0)" ::: "memory"); }
        SBAR();
        if (c + 2 < 32) {
            int nb = cur + 2; if (nb >= 3) nb -= 3;
            stage8k(Kh_g + (size_t)(c + 2) * 8192, 128, lds + nb * 8192, w, lane);
            stage8k(V_g + (size_t)(c + 2) * 128, 4096, lds + 24576 + nb * 8192, w, lane);
        }
        char* curK = lds + cur * 8192;
        char* curV = lds + 24576 + cur * 8192;
#pragma unroll
        for (int kf = 0; kf < 2; ++kf) {
            int kb = (wk * 32 + kf * 16 + c16) * 128 + kswz;
            s16x8 kh0 = *(const s16x8*)(curK + kb);
            s16x8 kh1 = *(const s16x8*)(curK + (kb ^ 64));
            s16x4 pb[2];
#pragma unroll
            for (int qf = 0; qf < 2; ++qf) {
                f32x4 s = {0.f, 0.f, 0.f, 0.f};
                s = mfma16(kh0, qh[qf][0], s);
                s = mfma16(kh1, qh[qf][1], s);
                float e0 = exp2f(s[0]);
                float e1 = exp2f(s[1]);
                float e2 = exp2f(s[2]);
                float e3 = exp2f(s[3]);
                lsum[qf] += (e0 + e1) + (e2 + e3);
                u32x2 pu = {permpack(e0, e1), permpack(e2, e3)};
                pb[qf] = __builtin_bit_cast(s16x4, pu);
                lacc[qf] = mfma16k16(onesf, pb[qf], lacc[qf]);
            }
            int vs = kf ? vsw1 : vsw0;
#pragma unroll
            for (int df = 0; df < 4; ++df) {
                s16x4 vf = *(const s16x4*)(curV + (df * 16 + c16) * 128 + vs);
                oacc[0][df] = mfma16k16(vf, pb[0], oacc[0][df]);
                oacc[1][df] = mfma16k16(vf, pb[1], oacc[1][df]);
            }
        }
        ++cur; if (cur == 3) cur = 0;
    }

    // reduce f32 lsum across the 4 k-groups (16 lanes each hold one q)
#pragma unroll
    for (int qf = 0; qf < 2; ++qf) {
        lsum[qf] += __shfl_xor(lsum[qf], 16, 64);
        lsum[qf] += __shfl_xor(lsum[qf], 32, 64);
    }
    __syncthreads();   // all compute done; staging region becomes sOf
#pragma unroll
    for (int qf = 0; qf < 2; ++qf)
        if (g == 0) {
            sL2t[wk * 128 + wq * 32 + qf * 16 + c16] = lacc[qf][0];
            sL2f[wk * 128 + wq * 32 + qf * 16 + c16] = lsum[qf];
        }

#pragma unroll
    for (int half = 0; half < 2; ++half) {
        if (half) __syncthreads();
        if ((wq >> 1) == half) {
            int qlocal = (wq & 1) * 32 + c16;
#pragma unroll
            for (int qf = 0; qf < 2; ++qf)
#pragma unroll
                for (int df = 0; df < 4; ++df)
#pragma unroll
                    for (int r = 0; r < 4; ++r)
                        sOf[wk * 4352 + (df * 16 + g * 4 + r) * 68 + qlocal + qf * 16] =
                            oacc[qf][df][r];
        }
        __syncthreads();
        {
            int q = t >> 3, dg = t & 7;
            float lt = sL2t[half * 64 + q] + sL2t[128 + half * 64 + q];
            float linv = 1.f / lt;
            u16x8 ov;
#pragma unroll
            for (int i = 0; i < 8; ++i) {
                int d = dg * 8 + i;
                ov[i] = f2bf((sOf[d * 68 + q] + sOf[4352 + d * 68 + q]) * linv);
            }
            *(u16x8*)&Att[(size_t)(b * SQL + qbase + half * 64 + q) * EMBED + h * 64 + dg * 8] = ov;
            if (dg == 0) {
                float lf = sL2f[half * 64 + q] + sL2f[128 + half * 64 + q];
                llog[(size_t)(b * 16 + h) * SQL + qbase + half * 64 + q] = log2f(lf);
            }
        }
    }
}

// ---------------------------------------------------------------------------
// Pass 2: mean_attn (Q pre-scaled: p = exp2(s - lb)). r14 structure.
// ---------------------------------------------------------------------------
__global__ __launch_bounds__(512, 4)
void attn_mean(const u16* __restrict__ Qhi, const u16* __restrict__ Khi,
               const float* __restrict__ llog, float* __restrict__ meanOut) {
    __shared__ char lds[81920];   // Q dbuf 2x16K @0; K tbuf 3x16K @32768

    const int t = threadIdx.x;
    const int w = t >> 6, lane = t & 63;
    const int g = lane >> 4, c16 = lane & 15;
    const int qt = blockIdx.x >> 6;
    const int low = blockIdx.x & 63;
    const int b = low >> 4, ks = low & 15;
    const int qbase = qt * 128;
    const int kbase = ks * 128;
    const int wq = w >> 1, wk = w & 1;
    const int kswz = (g ^ (c16 & 7)) << 4;

    const size_t QH_STRIDE = (size_t)SQL * 128;
    const size_t KH_STRIDE = (size_t)SKL * 128;
    const char* Qh_b = (const char*)(Qhi + ((size_t)(b * 16) * SQL + qbase) * 64);
    const char* Kh_b = (const char*)(Khi + ((size_t)(b * 16) * SKL + kbase) * 64);
    const float* ll_b = llog + (size_t)(b * 16) * SQL + qbase;

    f32x4 ma[2][4];
#pragma unroll
    for (int qf = 0; qf < 2; ++qf)
#pragma unroll
        for (int i = 0; i < 4; ++i) ma[qf][i] = (f32x4){0.f, 0.f, 0.f, 0.f};

    stage8k(Qh_b, 128, lds, w, lane);
    stage8k(Qh_b + 8192, 128, lds + 8192, w, lane);
    float lbA0 = ll_b[wq * 32 + c16];
    float lbA1 = ll_b[wq * 32 + 16 + c16];
    stage8k(Kh_b, 128, lds + 32768, w, lane);
    stage8k(Kh_b + 8192, 128, lds + 32768 + 8192, w, lane);
    stage8k(Qh_b + QH_STRIDE, 128, lds + 16384, w, lane);
    stage8k(Qh_b + QH_STRIDE + 8192, 128, lds + 16384 + 8192, w, lane);
    float lbB0 = ll_b[SQL + wq * 32 + c16];
    float lbB1 = ll_b[SQL + wq * 32 + 16 + c16];
    stage8k(Kh_b + KH_STRIDE, 128, lds + 32768 + 16384, w, lane);
    stage8k(Kh_b + KH_STRIDE + 8192, 128, lds + 32768 + 16384 + 8192, w, lane);

    int curK = 0;
    for (int h = 0; h < 16; ++h) {
        if (h < 15) { asm volatile("s_waitcnt vmcnt(4)" ::: "memory"); }
        else        { asm volatile("s_waitcnt vmcnt(0)" ::: "memory"); }
        SBAR();

        const char* sQ = lds + (h & 1) * 16384;
        s16x8 qa0, qa1, qc0, qc1;
        {
            int qb0 = (wq * 32 + c16) * 128 + kswz;
            qa0 = *(const s16x8*)(sQ + qb0);
            qa1 = *(const s16x8*)(sQ + (qb0 ^ 64));
            int qb1 = (wq * 32 + 16 + c16) * 128 + kswz;
            qc0 = *(const s16x8*)(sQ + qb1);
            qc1 = *(const s16x8*)(sQ + (qb1 ^ 64));
        }
        asm volatile("s_waitcnt lgkmcnt(0)" ::: "memory");
        SBAR();

        float lb0 = lbA0, lb1 = lbA1;
        lbA0 = lbB0; lbA1 = lbB1;

        if (h + 2 < 16) {
            const char* Qg = Qh_b + (size_t)(h + 2) * QH_STRIDE;
            char* qdst = lds + (h & 1) * 16384;
            stage8k(Qg, 128, qdst, w, lane);
            stage8k(Qg + 8192, 128, qdst + 8192, w, lane);
            lbB0 = ll_b[(size_t)(h + 2) * SQL + wq * 32 + c16];
            lbB1 = ll_b[(size_t)(h + 2) * SQL + wq * 32 + 16 + c16];
            const char* Kg = Kh_b + (size_t)(h + 2) * KH_STRIDE;
            int nb = curK + 2; if (nb >= 3) nb -= 3;
            char* kdst = lds + 32768 + nb * 16384;
            stage8k(Kg, 128, kdst, w, lane);
            stage8k(Kg + 8192, 128, kdst + 8192, w, lane);
        }

        const char* sK = lds + 32768 + curK * 16384;
#pragma unroll
        for (int kf = 0; kf < 4; ++kf) {
            int kb = (kf * 32 + wk * 16 + c16) * 128 + kswz;
            s16x8 kh0 = *(const s16x8*)(sK + kb);
            s16x8 kh1 = *(const s16x8*)(sK + (kb ^ 64));
            {
                f32x4 s = {0.f, 0.f, 0.f, 0.f};
                s = mfma16(kh0, qa0, s);
                s = mfma16(kh1, qa1, s);
                ma[0][kf][0] += exp2f(s[0] - lb0);
                ma[0][kf][1] += exp2f(s[1] - lb0);
                ma[0][kf][2] += exp2f(s[2] - lb0);
                ma[0][kf][3] += exp2f(s[3] - lb0);
            }
            {
                f32x4 s = {0.f, 0.f, 0.f, 0.f};
                s = mfma16(kh0, qc0, s);
                s = mfma16(kh1, qc1, s);
                ma[1][kf][0] += exp2f(s[0] - lb1);
                ma[1][kf][1] += exp2f(s[1] - lb1);
                ma[1][kf][2] += exp2f(s[2] - lb1);
                ma[1][kf][3] += exp2f(s[3] - lb1);
            }
        }
        ++curK; if (curK == 3) curK = 0;
    }

    const float s16c = 1.f / 16.f;
#pragma unroll
    for (int qf = 0; qf < 2; ++qf)
#pragma unroll
        for (int kf = 0; kf < 4; ++kf) {
            f32x4 m = ma[qf][kf];
            m[0] *= s16c; m[1] *= s16c; m[2] *= s16c; m[3] *= s16c;
            *(f32x4*)&meanOut[(size_t)(b * SQL + qbase + wq * 32 + qf * 16 + c16) * SKL +
                              kbase + kf * 32 + wk * 16 + g * 4] = m;
        }
}

// ---------------------------------------------------------------------------
extern "C" void kernel_launch(void* const* d_in, const int* in_sizes, int n_in,
                              void* d_out, int out_size, void* d_ws, size_t ws_size,
                              hipStream_t stream) {
    const float* query = (const float*)d_in[0];
    const float* key   = (const float*)d_in[1];
    const float* value = (const float*)d_in[2];
    const float* Wq = (const float*)d_in[3];
    const float* bq = (const float*)d_in[4];
    const float* Wk = (const float*)d_in[5];
    const float* bk = (const float*)d_in[6];
    const float* Wv = (const float*)d_in[7];
    const float* bv = (const float*)d_in[8];
    const float* Wo = (const float*)d_in[9];
    const float* bo = (const float*)d_in[10];

    float* out = (float*)d_out;                         // [4,1024,1024] f32
    float* meanOut = out + (size_t)BATCH * SQL * EMBED; // [4,1024,2048] f32

    u16* Qhi = (u16*)d_ws;                              // head-major [b][h][q][64], pre-scaled by PSC
    u16* Khi = Qhi + (size_t)4096 * 1024;               // [b][h][k][64]
    u16* VTh = Khi + (size_t)8192 * 1024;               // [b][h][d][2048]
    u16* Att = VTh + (size_t)8192 * 1024;               // [4096][1024] bf16
    float* llog = (float*)(Att + (size_t)4096 * 1024);  // [b*16+h][q]
    u16* Wqh = (u16*)(llog + 64 * 1024);                // bf16 weight planes
    u16* Wkh = Wqh + (size_t)1024 * 1024;
    u16* Wvh = Wkh + (size_t)1024 * 1024;
    u16* Woh = Wvh + (size_t)1024 * 1024;

    cvt_w<<<dim3(2048), 256, 0, stream>>>(Wq, Wk, Wv, Wo, Wqh, Wkh, Wvh, Woh);

    gemm_mfma<0, 1, 6><<<dim3(8, 32), 256, 0, stream>>>(query, Wqh, bq, Qhi, 4096, 1024, 10);
    gemm_mfma<0, 1, 5><<<dim3(8, 64), 256, 0, stream>>>(key, Wkh, bk, Khi, 8192, 1024, 11);
    gemm_mfma<1, 0, 4><<<dim3(64, 8), 256, 0, stream>>>(Wvh, value, bv, VTh, 1024, 8192, 0);

    attn_O<<<dim3(512), dim3(512), 0, stream>>>(Qhi, Khi, VTh, Att, llog);
    attn_mean<<<dim3(512), dim3(512), 0, stream>>>(Qhi, Khi, llog, meanOut);

    gemm_mfma<1, 1, 0><<<dim3(8, 32), 256, 0, stream>>>(Att, Woh, bo, out, 4096, 1024, 0);
}